// Round 6
// baseline (415.092 us; speedup 1.0000x reference)
//
#include <hip/hip_runtime.h>
#include <math.h>

#define NCLASS  10
#define NFEAT   64
#define CHUNK   1024          // rows per hist/scatter chunk
#define NCHUNK_MAX 512        // N=524288 -> 512 chunks
#define K1D_BPC 104           // blocks per class in k1d
#define NSHARD  16            // sharded M accumulators

// ws layout (4-byte units)
#define OFF_CNT  0                         // [16] int
#define OFF_PADO 16                        // [16] int
#define OFF_LDC  32                        // [16] float
#define OFF_PM   48                        // [48] float
#define OFF_PL   96                        // [48] float
#define OFF_MU   144                       // [640] float
#define OFF_SC   784                       // [10][4096] float
#define OFF_S    41744                     // [640] float, atomic accum  (zeroed)
#define OFF_MS   42384                     // [10][16][4096] float shards (zeroed)
#define OFF_HB   697744                    // [10][512] int
#define OFF_SIDX 702864                    // [N+640] int
#define ZERO_LO  OFF_S
#define ZERO_HI  (OFF_MS + NCLASS*NSHARD*4096)   // 697744

__device__ __forceinline__ float rlane(float v, int l) {
  return __int_as_float(__builtin_amdgcn_readlane(__float_as_int(v), l));
}

// ---------------------------------------------------------------- k1a: zero + per-chunk hist
__global__ __launch_bounds__(256) void k1a_hist(const int* __restrict__ T,
                                                float* __restrict__ ws, int N, int nchunk) {
  const int b = blockIdx.x, t = threadIdx.x;
  for (int z = ZERO_LO + b * 256 + t; z < ZERO_HI; z += nchunk * 256) ws[z] = 0.0f;
  __shared__ int h[NCLASS];
  if (t < NCLASS) h[t] = 0;
  __syncthreads();
  int start = b * CHUNK;
#pragma unroll
  for (int u = 0; u < 4; ++u) {
    int i = start + u * 256 + t;
    if (i < N) atomicAdd(&h[T[i]], 1);
  }
  __syncthreads();
  if (t < NCLASS) ((int*)(ws + OFF_HB))[t * NCHUNK_MAX + b] = h[t];  // transposed
}

// ---------------------------------------------------------------- k1b: parallel scan -> bases
__global__ __launch_bounds__(640) void k1b_scan(float* __restrict__ ws, int nchunk) {
  const int w = threadIdx.x >> 6;
  const int l = threadIdx.x & 63;
  int* Hg = (int*)(ws + OFF_HB);
  __shared__ int tot[NCLASS];
  int v[8], pre[8];
  int lanesum = 0;
#pragma unroll
  for (int u = 0; u < 8; ++u) {
    int b = l * 8 + u;
    v[u] = (b < nchunk) ? Hg[w * NCHUNK_MAX + b] : 0;
    pre[u] = lanesum;
    lanesum += v[u];
  }
  int incl = lanesum;
#pragma unroll
  for (int off = 1; off < 64; off <<= 1) {
    int t2 = __shfl_up(incl, off, 64);
    if (l >= off) incl += t2;
  }
  int excl = incl - lanesum;
  int ctot = __shfl(incl, 63, 64);
  if (l == 0) tot[w] = ctot;
  __syncthreads();
  int pado = 0;
#pragma unroll
  for (int c = 0; c < NCLASS; ++c)
    if (c < w) pado += (tot[c] + 63) & ~63;
#pragma unroll
  for (int u = 0; u < 8; ++u) {
    int b = l * 8 + u;
    if (b < nchunk) Hg[w * NCHUNK_MAX + b] = pado + excl + pre[u];
  }
  if (l == 0) {
    ((int*)(ws + OFF_CNT))[w] = ctot;
    ((int*)(ws + OFF_PADO))[w] = pado;
    if (w == NCLASS - 1) ((int*)(ws + OFF_PADO))[NCLASS] = pado + ((ctot + 63) & ~63);
  }
}

// ---------------------------------------------------------------- k1c: deterministic-base scatter
__global__ __launch_bounds__(256) void k1c_scatter(const int* __restrict__ T,
                                                   float* __restrict__ ws, int N) {
  __shared__ int lcnt[NCLASS], lbase[NCLASS];
  const int b = blockIdx.x, t = threadIdx.x;
  if (t < NCLASS) { lcnt[t] = 0; lbase[t] = ((const int*)(ws + OFF_HB))[t * NCHUNK_MAX + b]; }
  __syncthreads();
  int start = b * CHUNK;
  int tv[4], rk[4];
#pragma unroll
  for (int u = 0; u < 4; ++u) {
    int i = start + u * 256 + t;
    if (i < N) { tv[u] = T[i]; rk[u] = atomicAdd(&lcnt[tv[u]], 1); }
    else tv[u] = -1;
  }
  __syncthreads();
  int* sidx = (int*)(ws + OFF_SIDX);
#pragma unroll
  for (int u = 0; u < 4; ++u)
    if (tv[u] >= 0) sidx[lbase[tv[u]] + rk[u]] = start + u * 256 + t;
}

// ---------------------------------------------------------------- k1d: barrier-free per-class Gram
// grid (K1D_BPC, NCLASS), block 256 = 4 waves. Each wave owns a private dbuf LDS
// slab and its own 16-row micro-batches: NO __syncthreads in the main loop.
// Lane (li,lj) holds an 8x8 tile; epilogue merges 4 waves then atomicAdds into
// 1-of-16 shard accumulators (contention /16, RMW stays L2-resident).
__global__ __launch_bounds__(256, 3) void k1d_gram(const float* __restrict__ X,
                                                   float* __restrict__ ws) {
  __shared__ float buf[2][4][16][64];     // [dbuf][wave][row][col] = 32 KB
  const int c    = blockIdx.y;
  const int t    = threadIdx.x;
  const int w    = t >> 6, lane = t & 63;
  const int li   = lane >> 3, lj = lane & 7;
  const int rg4  = lane >> 4, c4 = lane & 15;   // staging: 4 rows x 16 float4-cols
  const int cnt  = ((const int*)(ws + OFF_CNT))[c];
  const int base = ((const int*)(ws + OFF_PADO))[c];
  const int* __restrict__ sidx = (const int*)(ws + OFF_SIDX);
  const float4* __restrict__ X4 = (const float4*)X;
  const int nmb = (cnt + 15) >> 4;              // 16-row micro-batches
  const int mb0 = blockIdx.x * 4 + w;
  const int MBS = K1D_BPC * 4;

  float acc[8][8];
#pragma unroll
  for (int i = 0; i < 8; ++i)
#pragma unroll
    for (int j = 0; j < 8; ++j) acc[i][j] = 0.0f;
  float4 csum = {0.f, 0.f, 0.f, 0.f};

  if (mb0 < nmb) {
#pragma unroll
    for (int u = 0; u < 4; ++u) {
      int p = (mb0 << 4) + u * 4 + rg4;
      float4 v = {0.f, 0.f, 0.f, 0.f};
      if (p < cnt) v = X4[(size_t)sidx[base + p] * 16 + c4];
      csum.x += v.x; csum.y += v.y; csum.z += v.z; csum.w += v.w;
      *(float4*)&buf[0][w][u * 4 + rg4][c4 * 4] = v;
    }
  }

  int cur = 0;
  for (int mb = mb0; mb < nmb; mb += MBS) {
    int nxt = mb + MBS;
    bool more = (nxt < nmb);
    float4 st[4];
    if (more) {
#pragma unroll
      for (int u = 0; u < 4; ++u) {
        int p = (nxt << 4) + u * 4 + rg4;
        float4 v = {0.f, 0.f, 0.f, 0.f};
        if (p < cnt) v = X4[(size_t)sidx[base + p] * 16 + c4];
        csum.x += v.x; csum.y += v.y; csum.z += v.z; csum.w += v.w;
        st[u] = v;
      }
    }
    const float* __restrict__ B = &buf[cur][w][0][0];   // wave-private: no barrier
#pragma unroll 2
    for (int r = 0; r < 16; ++r) {
      const float* row = B + r * 64;
      float a0[8], b0[8];
      *(float4*)&a0[0] = *(const float4*)(row + li * 8);
      *(float4*)&a0[4] = *(const float4*)(row + li * 8 + 4);
      *(float4*)&b0[0] = *(const float4*)(row + lj * 8);
      *(float4*)&b0[4] = *(const float4*)(row + lj * 8 + 4);
#pragma unroll
      for (int i = 0; i < 8; ++i)
#pragma unroll
        for (int j = 0; j < 8; ++j)
          acc[i][j] += a0[i] * b0[j];
    }
    if (more) {
#pragma unroll
      for (int u = 0; u < 4; ++u)
        *(float4*)&buf[cur ^ 1][w][u * 4 + rg4][c4 * 4] = st[u];
    }
    cur ^= 1;
  }
  __syncthreads();

  // epilogue: R = flat 4096 floats (buf[0]); colp = 1024 floats (buf[1] start)
  float* buff = &buf[0][0][0][0];
  float* R    = buff;
  float* colp = buff + 4096;
  *(float4*)&colp[(t >> 4) * 64 + (t & 15) * 4] = csum;   // [16][64] partials
  for (int ww = 0; ww < 4; ++ww) {
    if (w == ww) {
#pragma unroll
      for (int i = 0; i < 8; ++i)
#pragma unroll
        for (int j = 0; j < 8; ++j) {
          int ad = (li * 8 + i) * 64 + lj * 8 + j;
          if (ww == 0) R[ad] = acc[i][j]; else R[ad] += acc[i][j];
        }
    }
    __syncthreads();
  }

  float* Msh = ws + OFF_MS + (size_t)(c * NSHARD + (blockIdx.x % NSHARD)) * 4096;
  for (int e = t; e < 4096; e += 256) atomicAdd(&Msh[e], R[e]);
  if (t < 64) {
    float s = 0.0f;
#pragma unroll
    for (int g = 0; g < 16; ++g) s += colp[g * 64 + t];
    atomicAdd(&ws[OFF_S + c * 64 + t], s);
  }
}

// ---------------------------------------------------------------- k1e: reduce shards -> mu, Sc
__global__ __launch_bounds__(256) void k1e_cov(float* __restrict__ ws) {
  const int c = blockIdx.x, t = threadIdx.x;
  __shared__ float mu[64];
  float cnt = (float)((const int*)(ws + OFF_CNT))[c];
  if (t < 64) {
    float m = ws[OFF_S + c * 64 + t] / cnt;
    mu[t] = m;
    ws[OFF_MU + c * 64 + t] = m;
  }
  __syncthreads();
  float inv = 1.0f / (cnt - 1.0f);
  const float* Ms = ws + OFF_MS + (size_t)c * NSHARD * 4096;
  for (int e = t; e < 4096; e += 256) {
    float s = 0.0f;
#pragma unroll
    for (int sh = 0; sh < NSHARD; ++sh) s += Ms[sh * 4096 + e];
    int r = e >> 6, l = e & 63;
    ws[OFF_SC + c * 4096 + e] = (s - cnt * mu[r] * mu[l]) * inv;
  }
}

// ---------------------------------------------------------------- k2b: register Cholesky
// Sc symmetric -> lane i's row loads coalesced as column loads. No LDS, no barriers.
__global__ __launch_bounds__(64) void k2b_chol(float* __restrict__ ws) {
  const int lane = threadIdx.x;
  const int bid  = blockIdx.x;

  int ci, cj, p = -1;
  bool isPair = (bid >= NCLASS);
  if (!isPair) { ci = cj = bid; }
  else {
    p = bid - NCLASS;
    int rem = p, i = 0;
    while (rem >= 9 - i) { rem -= 9 - i; ++i; }
    ci = i; cj = i + 1 + rem;
  }

  const float* A = ws + OFF_SC + ci * 4096;
  const float* B = ws + OFF_SC + cj * 4096;
  float S[64];
#pragma unroll
  for (int q = 0; q < 64; ++q) {
    float v = A[q * 64 + lane];              // symmetric: row lane == col lane
    if (isPair) v = 0.5f * (v + B[q * 64 + lane]);
    S[q] = v;
  }
  float pi = isPair ? (ws[OFF_MU + ci * 64 + lane] - ws[OFF_MU + cj * 64 + lane]) : 0.0f;

  float logacc = 0.0f, s2 = 0.0f;
#pragma unroll
  for (int k = 0; k < 64; ++k) {
    float lkk = sqrtf(rlane(S[k], k));
    float inv = 1.0f / lkk;
    float lik = S[k] * inv;
    S[k] = lik;
    logacc += logf(lkk);
    float yk = rlane(pi, k) * inv;
    s2 += yk * yk;
    pi -= (lane > k) ? lik * yk : 0.0f;
#pragma unroll
    for (int j = k + 1; j < 64; ++j)
      S[j] -= lik * rlane(lik, j);
  }

  if (lane == 0) {
    if (isPair) {
      ws[OFF_PM + p] = s2 * 0.125f;
      ws[OFF_PL + p] = 2.0f * logacc;
    } else {
      ws[OFF_LDC + bid] = 2.0f * logacc;
    }
  }
}

// ---------------------------------------------------------------- k2c: final scalar
__global__ void k2c_final(const float* __restrict__ Ksamp,
                          const float* __restrict__ ws,
                          float* __restrict__ out) {
  __shared__ float ldc[10], pm[45], pl[45];
  __shared__ float Km[100], Sp[100], L[100], Inv[100], Aa[100];
  __shared__ float red[3];
  const int tid = threadIdx.x;
  const int k = 10;

  if (tid < 3) red[tid] = 0.0f;
  if (tid < 10) ldc[tid] = ws[OFF_LDC + tid];
  if (tid < 45) { pm[tid] = ws[OFF_PM + tid]; pl[tid] = ws[OFF_PL + tid]; }
  if (tid < 100) Sp[tid] = Ksamp[tid];
  __syncthreads();

  float s00 = Sp[0];
  if (tid < 100) {
    int i = tid / 10, j = tid % 10;
    float Kv;
    if (i == j) Kv = s00;
    else {
      int a = i < j ? i : j, b = i < j ? j : i;
      int pp = (a * (19 - a)) / 2 + (b - a - 1);
      float D = pm[pp] + 0.5f * (pl[pp] - 0.5f * (ldc[i] + ldc[j]));
      Kv = s00 * 0.5f * expf(-D * D * 100.0f);
    }
    Km[tid] = Kv;
    Aa[tid] = Kv;
  }
  __syncthreads();

  for (int kk = 0; kk < k; ++kk) {
    if (tid == kk) {
      float s = Sp[kk * k + kk];
      for (int m = 0; m < kk; ++m) s -= L[kk * k + m] * L[kk * k + m];
      L[kk * k + kk] = sqrtf(s);
    }
    __syncthreads();
    if (tid > kk && tid < k) {
      float v = Sp[tid * k + kk];
      for (int m = 0; m < kk; ++m) v -= L[tid * k + m] * L[kk * k + m];
      L[tid * k + kk] = v / L[kk * k + kk];
    }
    __syncthreads();
  }
  if (tid < k) atomicAdd(&red[0], 2.0f * logf(L[tid * k + tid]));

  if (tid < k) {
    float y[10], x[10];
    for (int r = 0; r < k; ++r) {
      float v = (r == tid) ? 1.0f : 0.0f;
      for (int m = 0; m < r; ++m) v -= L[r * k + m] * y[m];
      y[r] = v / L[r * k + r];
    }
    for (int r = k - 1; r >= 0; --r) {
      float v = y[r];
      for (int m = r + 1; m < k; ++m) v -= L[m * k + r] * x[m];
      x[r] = v / L[r * k + r];
    }
    for (int r = 0; r < k; ++r) Inv[r * k + tid] = x[r];
  }
  __syncthreads();
  if (tid < 100) atomicAdd(&red[1], Inv[tid] * Km[tid]);

  for (int kk = 0; kk < k; ++kk) {
    if (tid == 0) {
      int piv = kk; float mx = fabsf(Aa[kk * k + kk]);
      for (int r = kk + 1; r < k; ++r) {
        float v = fabsf(Aa[r * k + kk]);
        if (v > mx) { mx = v; piv = r; }
      }
      if (piv != kk)
        for (int c2 = 0; c2 < k; ++c2) {
          float tmp = Aa[kk * k + c2]; Aa[kk * k + c2] = Aa[piv * k + c2]; Aa[piv * k + c2] = tmp;
        }
      red[2] += logf(fabsf(Aa[kk * k + kk]));
    }
    __syncthreads();
    if (tid < 100) {
      int r = tid / 10, c2 = tid % 10;
      if (r > kk && c2 > kk)
        Aa[r * k + c2] -= Aa[r * k + kk] / Aa[kk * k + kk] * Aa[kk * k + c2];
    }
    __syncthreads();
  }

  if (tid == 0)
    out[0] = 0.5f * (red[1] - (float)k + red[0] - red[2]);
}

// ---------------------------------------------------------------- launch
extern "C" void kernel_launch(void* const* d_in, const int* in_sizes, int n_in,
                              void* d_out, int out_size, void* d_ws, size_t ws_size,
                              hipStream_t stream) {
  const float* X  = (const float*)d_in[0];
  const int*   T  = (const int*)d_in[1];
  const float* Ks = (const float*)d_in[2];
  float* out = (float*)d_out;
  float* ws  = (float*)d_ws;
  int N = in_sizes[1];
  int nchunk = (N + CHUNK - 1) / CHUNK;

  k1a_hist<<<nchunk, 256, 0, stream>>>(T, ws, N, nchunk);
  k1b_scan<<<1, 640, 0, stream>>>(ws, nchunk);
  k1c_scatter<<<nchunk, 256, 0, stream>>>(T, ws, N);
  k1d_gram<<<dim3(K1D_BPC, NCLASS), 256, 0, stream>>>(X, ws);
  k1e_cov<<<NCLASS, 256, 0, stream>>>(ws);
  k2b_chol<<<55, 64, 0, stream>>>(ws);
  k2c_final<<<1, 128, 0, stream>>>(Ks, ws, out);
}

// Round 7
// 321.409 us; speedup vs baseline: 1.2915x; 1.2915x over previous
//
#include <hip/hip_runtime.h>
#include <math.h>

#define NCLASS  10
#define NFEAT   64
#define CHUNK   1024          // rows per hist/scatter chunk
#define NCHUNK_MAX 512        // N=524288 -> 512 chunks
#define K1D_BPC 104           // blocks per class in k1d
#define NSHARD  16            // sharded M accumulators

// ws layout (4-byte units)
#define OFF_CNT  0                         // [16] int
#define OFF_PADO 16                        // [16] int
#define OFF_LDC  32                        // [16] float
#define OFF_PM   48                        // [48] float
#define OFF_PL   96                        // [48] float
#define OFF_MU   144                       // [640] float
#define OFF_SC   784                       // [10][4096] float
#define OFF_S    41744                     // [640] float, atomic accum  (zeroed)
#define OFF_MS   42384                     // [10][16][4096] float shards (zeroed)
#define OFF_HB   697744                    // [10][512] int
#define OFF_SIDX 702864                    // [N+640] int
#define ZERO_LO  OFF_S
#define ZERO_HI  (OFF_MS + NCLASS*NSHARD*4096)   // 697744

__device__ __forceinline__ float rlane(float v, int l) {
  return __int_as_float(__builtin_amdgcn_readlane(__float_as_int(v), l));
}

// ---------------------------------------------------------------- k1a: zero + per-chunk hist
__global__ __launch_bounds__(256) void k1a_hist(const int* __restrict__ T,
                                                float* __restrict__ ws, int N, int nchunk) {
  const int b = blockIdx.x, t = threadIdx.x;
  for (int z = ZERO_LO + b * 256 + t; z < ZERO_HI; z += nchunk * 256) ws[z] = 0.0f;
  __shared__ int h[NCLASS];
  if (t < NCLASS) h[t] = 0;
  __syncthreads();
  int start = b * CHUNK;
#pragma unroll
  for (int u = 0; u < 4; ++u) {
    int i = start + u * 256 + t;
    if (i < N) atomicAdd(&h[T[i]], 1);
  }
  __syncthreads();
  if (t < NCLASS) ((int*)(ws + OFF_HB))[t * NCHUNK_MAX + b] = h[t];  // transposed
}

// ---------------------------------------------------------------- k1b: parallel scan -> bases
__global__ __launch_bounds__(640) void k1b_scan(float* __restrict__ ws, int nchunk) {
  const int w = threadIdx.x >> 6;
  const int l = threadIdx.x & 63;
  int* Hg = (int*)(ws + OFF_HB);
  __shared__ int tot[NCLASS];
  int v[8], pre[8];
  int lanesum = 0;
#pragma unroll
  for (int u = 0; u < 8; ++u) {
    int b = l * 8 + u;
    v[u] = (b < nchunk) ? Hg[w * NCHUNK_MAX + b] : 0;
    pre[u] = lanesum;
    lanesum += v[u];
  }
  int incl = lanesum;
#pragma unroll
  for (int off = 1; off < 64; off <<= 1) {
    int t2 = __shfl_up(incl, off, 64);
    if (l >= off) incl += t2;
  }
  int excl = incl - lanesum;
  int ctot = __shfl(incl, 63, 64);
  if (l == 0) tot[w] = ctot;
  __syncthreads();
  int pado = 0;
#pragma unroll
  for (int c = 0; c < NCLASS; ++c)
    if (c < w) pado += (tot[c] + 63) & ~63;
#pragma unroll
  for (int u = 0; u < 8; ++u) {
    int b = l * 8 + u;
    if (b < nchunk) Hg[w * NCHUNK_MAX + b] = pado + excl + pre[u];
  }
  if (l == 0) {
    ((int*)(ws + OFF_CNT))[w] = ctot;
    ((int*)(ws + OFF_PADO))[w] = pado;
    if (w == NCLASS - 1) ((int*)(ws + OFF_PADO))[NCLASS] = pado + ((ctot + 63) & ~63);
  }
}

// ---------------------------------------------------------------- k1c: deterministic-base scatter
__global__ __launch_bounds__(256) void k1c_scatter(const int* __restrict__ T,
                                                   float* __restrict__ ws, int N) {
  __shared__ int lcnt[NCLASS], lbase[NCLASS];
  const int b = blockIdx.x, t = threadIdx.x;
  if (t < NCLASS) { lcnt[t] = 0; lbase[t] = ((const int*)(ws + OFF_HB))[t * NCHUNK_MAX + b]; }
  __syncthreads();
  int start = b * CHUNK;
  int tv[4], rk[4];
#pragma unroll
  for (int u = 0; u < 4; ++u) {
    int i = start + u * 256 + t;
    if (i < N) { tv[u] = T[i]; rk[u] = atomicAdd(&lcnt[tv[u]], 1); }
    else tv[u] = -1;
  }
  __syncthreads();
  int* sidx = (int*)(ws + OFF_SIDX);
#pragma unroll
  for (int u = 0; u < 4; ++u)
    if (tv[u] >= 0) sidx[lbase[tv[u]] + rk[u]] = start + u * 256 + t;
}

// ---------------------------------------------------------------- k1d: barrier-free per-class Gram
// Each wave owns a private dbuf LDS slab + its own 16-row micro-batches: no
// __syncthreads in the main loop. Epilogue merges 4 waves, atomicAdds into
// 1-of-16 shard accumulators (contention /16, RMW stays L2-resident).
__global__ __launch_bounds__(256, 3) void k1d_gram(const float* __restrict__ X,
                                                   float* __restrict__ ws) {
  __shared__ float buf[2][4][16][64];     // [dbuf][wave][row][col] = 32 KB
  const int c    = blockIdx.y;
  const int t    = threadIdx.x;
  const int w    = t >> 6, lane = t & 63;
  const int li   = lane >> 3, lj = lane & 7;
  const int rg4  = lane >> 4, c4 = lane & 15;
  const int cnt  = ((const int*)(ws + OFF_CNT))[c];
  const int base = ((const int*)(ws + OFF_PADO))[c];
  const int* __restrict__ sidx = (const int*)(ws + OFF_SIDX);
  const float4* __restrict__ X4 = (const float4*)X;
  const int nmb = (cnt + 15) >> 4;
  const int mb0 = blockIdx.x * 4 + w;
  const int MBS = K1D_BPC * 4;

  float acc[8][8];
#pragma unroll
  for (int i = 0; i < 8; ++i)
#pragma unroll
    for (int j = 0; j < 8; ++j) acc[i][j] = 0.0f;
  float4 csum = {0.f, 0.f, 0.f, 0.f};

  if (mb0 < nmb) {
#pragma unroll
    for (int u = 0; u < 4; ++u) {
      int p = (mb0 << 4) + u * 4 + rg4;
      float4 v = {0.f, 0.f, 0.f, 0.f};
      if (p < cnt) v = X4[(size_t)sidx[base + p] * 16 + c4];
      csum.x += v.x; csum.y += v.y; csum.z += v.z; csum.w += v.w;
      *(float4*)&buf[0][w][u * 4 + rg4][c4 * 4] = v;
    }
  }

  int cur = 0;
  for (int mb = mb0; mb < nmb; mb += MBS) {
    int nxt = mb + MBS;
    bool more = (nxt < nmb);
    float4 st[4];
    if (more) {
#pragma unroll
      for (int u = 0; u < 4; ++u) {
        int p = (nxt << 4) + u * 4 + rg4;
        float4 v = {0.f, 0.f, 0.f, 0.f};
        if (p < cnt) v = X4[(size_t)sidx[base + p] * 16 + c4];
        csum.x += v.x; csum.y += v.y; csum.z += v.z; csum.w += v.w;
        st[u] = v;
      }
    }
    const float* __restrict__ B = &buf[cur][w][0][0];   // wave-private: no barrier
#pragma unroll 2
    for (int r = 0; r < 16; ++r) {
      const float* row = B + r * 64;
      float a0[8], b0[8];
      *(float4*)&a0[0] = *(const float4*)(row + li * 8);
      *(float4*)&a0[4] = *(const float4*)(row + li * 8 + 4);
      *(float4*)&b0[0] = *(const float4*)(row + lj * 8);
      *(float4*)&b0[4] = *(const float4*)(row + lj * 8 + 4);
#pragma unroll
      for (int i = 0; i < 8; ++i)
#pragma unroll
        for (int j = 0; j < 8; ++j)
          acc[i][j] += a0[i] * b0[j];
    }
    if (more) {
#pragma unroll
      for (int u = 0; u < 4; ++u)
        *(float4*)&buf[cur ^ 1][w][u * 4 + rg4][c4 * 4] = st[u];
    }
    cur ^= 1;
  }
  __syncthreads();

  float* buff = &buf[0][0][0][0];
  float* R    = buff;
  float* colp = buff + 4096;
  *(float4*)&colp[(t >> 4) * 64 + (t & 15) * 4] = csum;
  for (int ww = 0; ww < 4; ++ww) {
    if (w == ww) {
#pragma unroll
      for (int i = 0; i < 8; ++i)
#pragma unroll
        for (int j = 0; j < 8; ++j) {
          int ad = (li * 8 + i) * 64 + lj * 8 + j;
          if (ww == 0) R[ad] = acc[i][j]; else R[ad] += acc[i][j];
        }
    }
    __syncthreads();
  }

  float* Msh = ws + OFF_MS + (size_t)(c * NSHARD + (blockIdx.x % NSHARD)) * 4096;
  for (int e = t; e < 4096; e += 256) atomicAdd(&Msh[e], R[e]);
  if (t < 64) {
    float s = 0.0f;
#pragma unroll
    for (int g = 0; g < 16; ++g) s += colp[g * 64 + t];
    atomicAdd(&ws[OFF_S + c * 64 + t], s);
  }
}

// ---------------------------------------------------------------- k1e: reduce shards -> mu, Sc
__global__ __launch_bounds__(256) void k1e_cov(float* __restrict__ ws) {
  const int c = blockIdx.x, t = threadIdx.x;
  __shared__ float mu[64];
  float cnt = (float)((const int*)(ws + OFF_CNT))[c];
  if (t < 64) {
    float m = ws[OFF_S + c * 64 + t] / cnt;
    mu[t] = m;
    ws[OFF_MU + c * 64 + t] = m;
  }
  __syncthreads();
  float inv = 1.0f / (cnt - 1.0f);
  const float* Ms = ws + OFF_MS + (size_t)c * NSHARD * 4096;
  for (int e = t; e < 4096; e += 256) {
    float s = 0.0f;
#pragma unroll
    for (int sh = 0; sh < NSHARD; ++sh) s += Ms[sh * 4096 + e];
    int r = e >> 6, l = e & 63;
    ws[OFF_SC + c * 4096 + e] = (s - cnt * mu[r] * mu[l]) * inv;
  }
}

// ---------------------------------------------------------------- k2b: register Cholesky
// R5-proven structure: global -> LDS tile -> float4 register loads -> register
// Cholesky with readlane broadcasts. (R6's direct-global init spilled S[] to
// scratch: VGPR_Count=72, 143us. Keep the LDS round-trip — it keeps S in regs.)
__global__ __launch_bounds__(64) void k2b_chol(float* __restrict__ ws) {
  __shared__ float Sld[64][65];
  const int lane = threadIdx.x;
  const int bid  = blockIdx.x;

  int ci, cj, p = -1;
  bool isPair = (bid >= NCLASS);
  if (!isPair) { ci = cj = bid; }
  else {
    p = bid - NCLASS;
    int rem = p, i = 0;
    while (rem >= 9 - i) { rem -= 9 - i; ++i; }
    ci = i; cj = i + 1 + rem;
  }

  const float* A = ws + OFF_SC + ci * 4096;
  const float* B = ws + OFF_SC + cj * 4096;
  for (int r = 0; r < 64; ++r) {
    float v = A[r * 64 + lane];
    if (isPair) v = 0.5f * (v + B[r * 64 + lane]);
    Sld[r][lane] = v;
  }
  float pi = isPair ? (ws[OFF_MU + ci * 64 + lane] - ws[OFF_MU + cj * 64 + lane]) : 0.0f;
  __syncthreads();

  float S[64];
#pragma unroll
  for (int q = 0; q < 16; ++q)
    *(float4*)&S[q * 4] = *(const float4*)&Sld[lane][q * 4];

  float logacc = 0.0f, s2 = 0.0f;
#pragma unroll
  for (int k = 0; k < 64; ++k) {
    float lkk = sqrtf(rlane(S[k], k));
    float inv = 1.0f / lkk;
    float lik = S[k] * inv;
    S[k] = lik;
    logacc += logf(lkk);
    float yk = rlane(pi, k) * inv;
    s2 += yk * yk;
    pi -= (lane > k) ? lik * yk : 0.0f;
#pragma unroll
    for (int j = k + 1; j < 64; ++j)
      S[j] -= lik * rlane(lik, j);
  }

  if (lane == 0) {
    if (isPair) {
      ws[OFF_PM + p] = s2 * 0.125f;
      ws[OFF_PL + p] = 2.0f * logacc;
    } else {
      ws[OFF_LDC + bid] = 2.0f * logacc;
    }
  }
}

// ---------------------------------------------------------------- k2c: final scalar
__global__ void k2c_final(const float* __restrict__ Ksamp,
                          const float* __restrict__ ws,
                          float* __restrict__ out) {
  __shared__ float ldc[10], pm[45], pl[45];
  __shared__ float Km[100], Sp[100], L[100], Inv[100], Aa[100];
  __shared__ float red[3];
  const int tid = threadIdx.x;
  const int k = 10;

  if (tid < 3) red[tid] = 0.0f;
  if (tid < 10) ldc[tid] = ws[OFF_LDC + tid];
  if (tid < 45) { pm[tid] = ws[OFF_PM + tid]; pl[tid] = ws[OFF_PL + tid]; }
  if (tid < 100) Sp[tid] = Ksamp[tid];
  __syncthreads();

  float s00 = Sp[0];
  if (tid < 100) {
    int i = tid / 10, j = tid % 10;
    float Kv;
    if (i == j) Kv = s00;
    else {
      int a = i < j ? i : j, b = i < j ? j : i;
      int pp = (a * (19 - a)) / 2 + (b - a - 1);
      float D = pm[pp] + 0.5f * (pl[pp] - 0.5f * (ldc[i] + ldc[j]));
      Kv = s00 * 0.5f * expf(-D * D * 100.0f);
    }
    Km[tid] = Kv;
    Aa[tid] = Kv;
  }
  __syncthreads();

  for (int kk = 0; kk < k; ++kk) {
    if (tid == kk) {
      float s = Sp[kk * k + kk];
      for (int m = 0; m < kk; ++m) s -= L[kk * k + m] * L[kk * k + m];
      L[kk * k + kk] = sqrtf(s);
    }
    __syncthreads();
    if (tid > kk && tid < k) {
      float v = Sp[tid * k + kk];
      for (int m = 0; m < kk; ++m) v -= L[tid * k + m] * L[kk * k + m];
      L[tid * k + kk] = v / L[kk * k + kk];
    }
    __syncthreads();
  }
  if (tid < k) atomicAdd(&red[0], 2.0f * logf(L[tid * k + tid]));

  if (tid < k) {
    float y[10], x[10];
    for (int r = 0; r < k; ++r) {
      float v = (r == tid) ? 1.0f : 0.0f;
      for (int m = 0; m < r; ++m) v -= L[r * k + m] * y[m];
      y[r] = v / L[r * k + r];
    }
    for (int r = k - 1; r >= 0; --r) {
      float v = y[r];
      for (int m = r + 1; m < k; ++m) v -= L[m * k + r] * x[m];
      x[r] = v / L[r * k + r];
    }
    for (int r = 0; r < k; ++r) Inv[r * k + tid] = x[r];
  }
  __syncthreads();
  if (tid < 100) atomicAdd(&red[1], Inv[tid] * Km[tid]);

  for (int kk = 0; kk < k; ++kk) {
    if (tid == 0) {
      int piv = kk; float mx = fabsf(Aa[kk * k + kk]);
      for (int r = kk + 1; r < k; ++r) {
        float v = fabsf(Aa[r * k + kk]);
        if (v > mx) { mx = v; piv = r; }
      }
      if (piv != kk)
        for (int c2 = 0; c2 < k; ++c2) {
          float tmp = Aa[kk * k + c2]; Aa[kk * k + c2] = Aa[piv * k + c2]; Aa[piv * k + c2] = tmp;
        }
      red[2] += logf(fabsf(Aa[kk * k + kk]));
    }
    __syncthreads();
    if (tid < 100) {
      int r = tid / 10, c2 = tid % 10;
      if (r > kk && c2 > kk)
        Aa[r * k + c2] -= Aa[r * k + kk] / Aa[kk * k + kk] * Aa[kk * k + c2];
    }
    __syncthreads();
  }

  if (tid == 0)
    out[0] = 0.5f * (red[1] - (float)k + red[0] - red[2]);
}

// ---------------------------------------------------------------- launch
extern "C" void kernel_launch(void* const* d_in, const int* in_sizes, int n_in,
                              void* d_out, int out_size, void* d_ws, size_t ws_size,
                              hipStream_t stream) {
  const float* X  = (const float*)d_in[0];
  const int*   T  = (const int*)d_in[1];
  const float* Ks = (const float*)d_in[2];
  float* out = (float*)d_out;
  float* ws  = (float*)d_ws;
  int N = in_sizes[1];
  int nchunk = (N + CHUNK - 1) / CHUNK;

  k1a_hist<<<nchunk, 256, 0, stream>>>(T, ws, N, nchunk);
  k1b_scan<<<1, 640, 0, stream>>>(ws, nchunk);
  k1c_scatter<<<nchunk, 256, 0, stream>>>(T, ws, N);
  k1d_gram<<<dim3(K1D_BPC, NCLASS), 256, 0, stream>>>(X, ws);
  k1e_cov<<<NCLASS, 256, 0, stream>>>(ws);
  k2b_chol<<<55, 64, 0, stream>>>(ws);
  k2c_final<<<1, 128, 0, stream>>>(Ks, ws, out);
}

// Round 8
// 300.982 us; speedup vs baseline: 1.3791x; 1.0679x over previous
//
#include <hip/hip_runtime.h>
#include <math.h>

#define NCLASS  10
#define NFEAT   64
#define CHUNK   1024          // rows per hist/scatter chunk
#define NCHUNK_MAX 512        // N=524288 -> 512 chunks
#define K1D_BPC 104           // blocks per class in k1d
#define NSHARD  16            // sharded M accumulators

// ws layout (4-byte units)
#define OFF_CNT  0                         // [16] int
#define OFF_PADO 16                        // [16] int
#define OFF_LDC  32                        // [16] float
#define OFF_PM   48                        // [48] float
#define OFF_PL   96                        // [48] float
#define OFF_MU   144                       // [640] float
#define OFF_SC   784                       // [10][4096] float
#define OFF_S    41744                     // [640] float, atomic accum  (zeroed)
#define OFF_MS   42384                     // [10][16][4096] float shards (zeroed)
#define OFF_HB   697744                    // [10][512] int
#define OFF_SIDX 702864                    // [N+640] int
#define ZERO_LO  OFF_S
#define ZERO_HI  (OFF_MS + NCLASS*NSHARD*4096)

typedef short  s8v  __attribute__((ext_vector_type(8)));
typedef short  s4v  __attribute__((ext_vector_type(4)));
typedef float  f16v __attribute__((ext_vector_type(16)));

__device__ __forceinline__ float rlane(float v, int l) {
  return __int_as_float(__builtin_amdgcn_readlane(__float_as_int(v), l));
}
__device__ __forceinline__ unsigned short f2bf(float x) {   // RNE truncate to bf16
  union { float f; unsigned u; } v; v.f = x;
  unsigned r = v.u + 0x7fffu + ((v.u >> 16) & 1u);
  return (unsigned short)(r >> 16);
}
__device__ __forceinline__ float bf2f(unsigned short b) {
  union { float f; unsigned u; } v; v.u = ((unsigned)b) << 16;
  return v.f;
}

// ---------------------------------------------------------------- k1a: zero + per-chunk hist
__global__ __launch_bounds__(256) void k1a_hist(const int* __restrict__ T,
                                                float* __restrict__ ws, int N, int nchunk) {
  const int b = blockIdx.x, t = threadIdx.x;
  for (int z = ZERO_LO + b * 256 + t; z < ZERO_HI; z += nchunk * 256) ws[z] = 0.0f;
  __shared__ int h[NCLASS];
  if (t < NCLASS) h[t] = 0;
  __syncthreads();
  int start = b * CHUNK;
#pragma unroll
  for (int u = 0; u < 4; ++u) {
    int i = start + u * 256 + t;
    if (i < N) atomicAdd(&h[T[i]], 1);
  }
  __syncthreads();
  if (t < NCLASS) ((int*)(ws + OFF_HB))[t * NCHUNK_MAX + b] = h[t];
}

// ---------------------------------------------------------------- k1b: parallel scan -> bases
__global__ __launch_bounds__(640) void k1b_scan(float* __restrict__ ws, int nchunk) {
  const int w = threadIdx.x >> 6;
  const int l = threadIdx.x & 63;
  int* Hg = (int*)(ws + OFF_HB);
  __shared__ int tot[NCLASS];
  int v[8], pre[8];
  int lanesum = 0;
#pragma unroll
  for (int u = 0; u < 8; ++u) {
    int b = l * 8 + u;
    v[u] = (b < nchunk) ? Hg[w * NCHUNK_MAX + b] : 0;
    pre[u] = lanesum;
    lanesum += v[u];
  }
  int incl = lanesum;
#pragma unroll
  for (int off = 1; off < 64; off <<= 1) {
    int t2 = __shfl_up(incl, off, 64);
    if (l >= off) incl += t2;
  }
  int excl = incl - lanesum;
  int ctot = __shfl(incl, 63, 64);
  if (l == 0) tot[w] = ctot;
  __syncthreads();
  int pado = 0;
#pragma unroll
  for (int c = 0; c < NCLASS; ++c)
    if (c < w) pado += (tot[c] + 63) & ~63;
#pragma unroll
  for (int u = 0; u < 8; ++u) {
    int b = l * 8 + u;
    if (b < nchunk) Hg[w * NCHUNK_MAX + b] = pado + excl + pre[u];
  }
  if (l == 0) {
    ((int*)(ws + OFF_CNT))[w] = ctot;
    ((int*)(ws + OFF_PADO))[w] = pado;
    if (w == NCLASS - 1) ((int*)(ws + OFF_PADO))[NCLASS] = pado + ((ctot + 63) & ~63);
  }
}

// ---------------------------------------------------------------- k1c: deterministic-base scatter
__global__ __launch_bounds__(256) void k1c_scatter(const int* __restrict__ T,
                                                   float* __restrict__ ws, int N) {
  __shared__ int lcnt[NCLASS], lbase[NCLASS];
  const int b = blockIdx.x, t = threadIdx.x;
  if (t < NCLASS) { lcnt[t] = 0; lbase[t] = ((const int*)(ws + OFF_HB))[t * NCHUNK_MAX + b]; }
  __syncthreads();
  int start = b * CHUNK;
  int tv[4], rk[4];
#pragma unroll
  for (int u = 0; u < 4; ++u) {
    int i = start + u * 256 + t;
    if (i < N) { tv[u] = T[i]; rk[u] = atomicAdd(&lcnt[tv[u]], 1); }
    else tv[u] = -1;
  }
  __syncthreads();
  int* sidx = (int*)(ws + OFF_SIDX);
#pragma unroll
  for (int u = 0; u < 4; ++u)
    if (tv[u] >= 0) sidx[lbase[tv[u]] + rk[u]] = start + u * 256 + t;
}

// ---------------------------------------------------------------- k1d: MFMA split-bf16 Gram
// Block = 256 thr = 4 waves, one 64-row batch at a time (double-buffered).
// Stage X tile TRANSPOSED in LDS as bf16 hi+lo planes [feat][row], stride 72,
// 8-row blocks XOR-swizzled by (feat>>3) for conflict-free b64 writes/b128 reads.
// Wave w computes 32x32 quadrant (wi=w>>1, wj=w&1) of the 64x64 Gram with
// v_mfma_f32_32x32x16_bf16: per K-step one b128/operand/plane, 3 MFMAs
// (HH + HL + LH; LL ~2^-18 rel, dropped). fp32 exact products, fp32 accum.
__global__ __launch_bounds__(256, 4) void k1d_gram(const float* __restrict__ X,
                                                   float* __restrict__ ws) {
  __shared__ __align__(16) short Ab[2][2][64 * 72];   // [dbuf][hi/lo][feat*72+row'] 36864B
  const int c    = blockIdx.y;
  const int t    = threadIdx.x;
  const int w    = t >> 6, lane = t & 63;
  const int wi   = w >> 1, wj = w & 1;
  const int mcol = lane & 31, khalf = lane >> 5;
  const int rq   = t >> 4, fq = t & 15;      // staging: row-quad, feat-quad
  const int cnt  = ((const int*)(ws + OFF_CNT))[c];
  const int base = ((const int*)(ws + OFF_PADO))[c];
  const int* __restrict__ sidx = (const int*)(ws + OFF_SIDX);
  const float4* __restrict__ X4 = (const float4*)X;
  const int nmb = (cnt + 63) >> 6;

  f16v acc = {};
  float csum[4] = {0.f, 0.f, 0.f, 0.f};
  float4 pv[4];

  const int mb0 = blockIdx.x;
  if (mb0 < nmb) {
#pragma unroll
    for (int j = 0; j < 4; ++j) {
      int p = (mb0 << 6) + rq * 4 + j;
      float4 v = {0.f, 0.f, 0.f, 0.f};
      if (p < cnt) v = X4[(size_t)sidx[base + p] * 16 + fq];
      pv[j] = v;
    }
    // write batch mb0 into buffer 0
    {
      short* hi = &Ab[0][0][0];
      short* lo = &Ab[0][1][0];
#pragma unroll
      for (int e = 0; e < 4; ++e) {
        int feat = fq * 4 + e;
        float x0 = (&pv[0].x)[e], x1 = (&pv[1].x)[e], x2 = (&pv[2].x)[e], x3 = (&pv[3].x)[e];
        csum[e] += x0 + x1 + x2 + x3;
        unsigned short h0 = f2bf(x0), h1 = f2bf(x1), h2 = f2bf(x2), h3 = f2bf(x3);
        s4v hv = {(short)h0, (short)h1, (short)h2, (short)h3};
        s4v lv = {(short)f2bf(x0 - bf2f(h0)), (short)f2bf(x1 - bf2f(h1)),
                  (short)f2bf(x2 - bf2f(h2)), (short)f2bf(x3 - bf2f(h3))};
        int off = feat * 72 + (((rq >> 1) ^ (feat >> 3)) << 3) + ((rq & 1) << 2);
        *(s4v*)(hi + off) = hv;
        *(s4v*)(lo + off) = lv;
      }
    }
  }

  int cur = 0;
  for (int mb = mb0; mb < nmb; mb += K1D_BPC) {
    int nxt = mb + K1D_BPC;
    bool more = (nxt < nmb);
    if (more) {
#pragma unroll
      for (int j = 0; j < 4; ++j) {
        int p = (nxt << 6) + rq * 4 + j;
        float4 v = {0.f, 0.f, 0.f, 0.f};
        if (p < cnt) v = X4[(size_t)sidx[base + p] * 16 + fq];
        pv[j] = v;
      }
    }
    __syncthreads();                          // staged writes to Ab[cur] visible
    {
      const short* hi = &Ab[cur][0][0];
      const short* lo = &Ab[cur][1][0];
      const int fA = wi * 32 + mcol;
      const int fB = wj * 32 + mcol;
#pragma unroll
      for (int ks = 0; ks < 4; ++ks) {
        int rb = ks * 2 + khalf;
        int offA = fA * 72 + ((rb ^ (fA >> 3)) << 3);
        int offB = fB * 72 + ((rb ^ (fB >> 3)) << 3);
        s8v aH = *(const s8v*)(hi + offA);
        s8v aL = *(const s8v*)(lo + offA);
        s8v bH = *(const s8v*)(hi + offB);
        s8v bL = *(const s8v*)(lo + offB);
        acc = __builtin_amdgcn_mfma_f32_32x32x16_bf16(aH, bH, acc, 0, 0, 0);
        acc = __builtin_amdgcn_mfma_f32_32x32x16_bf16(aH, bL, acc, 0, 0, 0);
        acc = __builtin_amdgcn_mfma_f32_32x32x16_bf16(aL, bH, acc, 0, 0, 0);
      }
    }
    if (more) {
      short* hi = &Ab[cur ^ 1][0][0];
      short* lo = &Ab[cur ^ 1][1][0];
#pragma unroll
      for (int e = 0; e < 4; ++e) {
        int feat = fq * 4 + e;
        float x0 = (&pv[0].x)[e], x1 = (&pv[1].x)[e], x2 = (&pv[2].x)[e], x3 = (&pv[3].x)[e];
        csum[e] += x0 + x1 + x2 + x3;
        unsigned short h0 = f2bf(x0), h1 = f2bf(x1), h2 = f2bf(x2), h3 = f2bf(x3);
        s4v hv = {(short)h0, (short)h1, (short)h2, (short)h3};
        s4v lv = {(short)f2bf(x0 - bf2f(h0)), (short)f2bf(x1 - bf2f(h1)),
                  (short)f2bf(x2 - bf2f(h2)), (short)f2bf(x3 - bf2f(h3))};
        int off = feat * 72 + (((rq >> 1) ^ (feat >> 3)) << 3) + ((rq & 1) << 2);
        *(s4v*)(hi + off) = hv;
        *(s4v*)(lo + off) = lv;
      }
    }
    cur ^= 1;
  }
  __syncthreads();

  // column-sum reduce via LDS scratch (reuse Ab)
  float* fl = (float*)&Ab[0][0][0];
  *(float4*)&fl[t * 4] = *(float4*)csum;      // hmm csum is scalar array; see below
  __syncthreads();
  if (t < 64) {
    float s = 0.0f;
#pragma unroll
    for (int r = 0; r < 16; ++r) s += fl[(r * 16 + (t >> 2)) * 4 + (t & 3)];
    atomicAdd(&ws[OFF_S + c * 64 + t], s);
  }

  // Gram quadrant -> shard accumulator (C/D: col=lane&31, row=(r&3)+8*(r>>2)+4*khalf)
  float* Msh = ws + OFF_MS + (size_t)(c * NSHARD + (blockIdx.x & (NSHARD - 1))) * 4096;
#pragma unroll
  for (int r = 0; r < 16; ++r) {
    int fr = wi * 32 + (r & 3) + 8 * (r >> 2) + 4 * khalf;
    int fc = wj * 32 + mcol;
    atomicAdd(&Msh[fr * 64 + fc], acc[r]);
  }
}

// ---------------------------------------------------------------- k1e: reduce shards -> mu, Sc
__global__ __launch_bounds__(256) void k1e_cov(float* __restrict__ ws) {
  const int c = blockIdx.x, t = threadIdx.x;
  __shared__ float mu[64];
  float cnt = (float)((const int*)(ws + OFF_CNT))[c];
  if (t < 64) {
    float m = ws[OFF_S + c * 64 + t] / cnt;
    mu[t] = m;
    ws[OFF_MU + c * 64 + t] = m;
  }
  __syncthreads();
  float inv = 1.0f / (cnt - 1.0f);
  const float* Ms = ws + OFF_MS + (size_t)c * NSHARD * 4096;
  for (int e = t; e < 4096; e += 256) {
    float s = 0.0f;
#pragma unroll
    for (int sh = 0; sh < NSHARD; ++sh) s += Ms[sh * 4096 + e];
    int r = e >> 6, l = e & 63;
    ws[OFF_SC + c * 4096 + e] = (s - cnt * mu[r] * mu[l]) * inv;
  }
}

// ---------------------------------------------------------------- k2b: register Cholesky
// R5-proven: global -> LDS tile -> float4 reg loads -> register Cholesky with
// readlane broadcasts. (Direct-global init spills S[] to scratch — keep LDS hop.)
__global__ __launch_bounds__(64) void k2b_chol(float* __restrict__ ws) {
  __shared__ float Sld[64][65];
  const int lane = threadIdx.x;
  const int bid  = blockIdx.x;

  int ci, cj, p = -1;
  bool isPair = (bid >= NCLASS);
  if (!isPair) { ci = cj = bid; }
  else {
    p = bid - NCLASS;
    int rem = p, i = 0;
    while (rem >= 9 - i) { rem -= 9 - i; ++i; }
    ci = i; cj = i + 1 + rem;
  }

  const float* A = ws + OFF_SC + ci * 4096;
  const float* B = ws + OFF_SC + cj * 4096;
  for (int r = 0; r < 64; ++r) {
    float v = A[r * 64 + lane];
    if (isPair) v = 0.5f * (v + B[r * 64 + lane]);
    Sld[r][lane] = v;
  }
  float pi = isPair ? (ws[OFF_MU + ci * 64 + lane] - ws[OFF_MU + cj * 64 + lane]) : 0.0f;
  __syncthreads();

  float S[64];
#pragma unroll
  for (int q = 0; q < 16; ++q)
    *(float4*)&S[q * 4] = *(const float4*)&Sld[lane][q * 4];

  float logacc = 0.0f, s2 = 0.0f;
#pragma unroll
  for (int k = 0; k < 64; ++k) {
    float lkk = sqrtf(rlane(S[k], k));
    float inv = 1.0f / lkk;
    float lik = S[k] * inv;
    S[k] = lik;
    logacc += logf(lkk);
    float yk = rlane(pi, k) * inv;
    s2 += yk * yk;
    pi -= (lane > k) ? lik * yk : 0.0f;
#pragma unroll
    for (int j = k + 1; j < 64; ++j)
      S[j] -= lik * rlane(lik, j);
  }

  if (lane == 0) {
    if (isPair) {
      ws[OFF_PM + p] = s2 * 0.125f;
      ws[OFF_PL + p] = 2.0f * logacc;
    } else {
      ws[OFF_LDC + bid] = 2.0f * logacc;
    }
  }
}

// ---------------------------------------------------------------- k2c: final scalar
__global__ void k2c_final(const float* __restrict__ Ksamp,
                          const float* __restrict__ ws,
                          float* __restrict__ out) {
  __shared__ float ldc[10], pm[45], pl[45];
  __shared__ float Km[100], Sp[100], L[100], Inv[100], Aa[100];
  __shared__ float red[3];
  const int tid = threadIdx.x;
  const int k = 10;

  if (tid < 3) red[tid] = 0.0f;
  if (tid < 10) ldc[tid] = ws[OFF_LDC + tid];
  if (tid < 45) { pm[tid] = ws[OFF_PM + tid]; pl[tid] = ws[OFF_PL + tid]; }
  if (tid < 100) Sp[tid] = Ksamp[tid];
  __syncthreads();

  float s00 = Sp[0];
  if (tid < 100) {
    int i = tid / 10, j = tid % 10;
    float Kv;
    if (i == j) Kv = s00;
    else {
      int a = i < j ? i : j, b = i < j ? j : i;
      int pp = (a * (19 - a)) / 2 + (b - a - 1);
      float D = pm[pp] + 0.5f * (pl[pp] - 0.5f * (ldc[i] + ldc[j]));
      Kv = s00 * 0.5f * expf(-D * D * 100.0f);
    }
    Km[tid] = Kv;
    Aa[tid] = Kv;
  }
  __syncthreads();

  for (int kk = 0; kk < k; ++kk) {
    if (tid == kk) {
      float s = Sp[kk * k + kk];
      for (int m = 0; m < kk; ++m) s -= L[kk * k + m] * L[kk * k + m];
      L[kk * k + kk] = sqrtf(s);
    }
    __syncthreads();
    if (tid > kk && tid < k) {
      float v = Sp[tid * k + kk];
      for (int m = 0; m < kk; ++m) v -= L[tid * k + m] * L[kk * k + m];
      L[tid * k + kk] = v / L[kk * k + kk];
    }
    __syncthreads();
  }
  if (tid < k) atomicAdd(&red[0], 2.0f * logf(L[tid * k + tid]));

  if (tid < k) {
    float y[10], x[10];
    for (int r = 0; r < k; ++r) {
      float v = (r == tid) ? 1.0f : 0.0f;
      for (int m = 0; m < r; ++m) v -= L[r * k + m] * y[m];
      y[r] = v / L[r * k + r];
    }
    for (int r = k - 1; r >= 0; --r) {
      float v = y[r];
      for (int m = r + 1; m < k; ++m) v -= L[m * k + r] * x[m];
      x[r] = v / L[r * k + r];
    }
    for (int r = 0; r < k; ++r) Inv[r * k + tid] = x[r];
  }
  __syncthreads();
  if (tid < 100) atomicAdd(&red[1], Inv[tid] * Km[tid]);

  for (int kk = 0; kk < k; ++kk) {
    if (tid == 0) {
      int piv = kk; float mx = fabsf(Aa[kk * k + kk]);
      for (int r = kk + 1; r < k; ++r) {
        float v = fabsf(Aa[r * k + kk]);
        if (v > mx) { mx = v; piv = r; }
      }
      if (piv != kk)
        for (int c2 = 0; c2 < k; ++c2) {
          float tmp = Aa[kk * k + c2]; Aa[kk * k + c2] = Aa[piv * k + c2]; Aa[piv * k + c2] = tmp;
        }
      red[2] += logf(fabsf(Aa[kk * k + kk]));
    }
    __syncthreads();
    if (tid < 100) {
      int r = tid / 10, c2 = tid % 10;
      if (r > kk && c2 > kk)
        Aa[r * k + c2] -= Aa[r * k + kk] / Aa[kk * k + kk] * Aa[kk * k + c2];
    }
    __syncthreads();
  }

  if (tid == 0)
    out[0] = 0.5f * (red[1] - (float)k + red[0] - red[2]);
}

// ---------------------------------------------------------------- launch
extern "C" void kernel_launch(void* const* d_in, const int* in_sizes, int n_in,
                              void* d_out, int out_size, void* d_ws, size_t ws_size,
                              hipStream_t stream) {
  const float* X  = (const float*)d_in[0];
  const int*   T  = (const int*)d_in[1];
  const float* Ks = (const float*)d_in[2];
  float* out = (float*)d_out;
  float* ws  = (float*)d_ws;
  int N = in_sizes[1];
  int nchunk = (N + CHUNK - 1) / CHUNK;

  k1a_hist<<<nchunk, 256, 0, stream>>>(T, ws, N, nchunk);
  k1b_scan<<<1, 640, 0, stream>>>(ws, nchunk);
  k1c_scatter<<<nchunk, 256, 0, stream>>>(T, ws, N);
  k1d_gram<<<dim3(K1D_BPC, NCLASS), 256, 0, stream>>>(X, ws);
  k1e_cov<<<NCLASS, 256, 0, stream>>>(ws);
  k2b_chol<<<55, 64, 0, stream>>>(ws);
  k2c_final<<<1, 128, 0, stream>>>(Ks, ws, out);
}